// Round 7
// baseline (263.558 us; speedup 1.0000x reference)
//
#include <hip/hip_runtime.h>

// ---------------------------------------------------------------------------
// MoE cross-attention decoder layer on MI355X (gfx950), bf16 MFMA pipeline.
// R7: QKV GEMM = R5 128x128 double-buffered structure + R6 ni-inner epilogue
// (write-amp fix) + fused f32->bf16 A-staging (reads tgt/qpos/mem/pos f32
// directly, converts in-register, ds_write_b128 to LDS) -> the big cvt pass
// is gone (weights-only cvt remains). W side still global_load_lds.
// Attention/combine/gemm_o/finalize unchanged from R4/R6.
// ---------------------------------------------------------------------------

typedef __bf16 bf16x8 __attribute__((ext_vector_type(8)));
typedef float f32x4 __attribute__((ext_vector_type(4)));
typedef unsigned int u32x4 __attribute__((ext_vector_type(4)));
typedef unsigned int u32x2 __attribute__((ext_vector_type(2)));
typedef unsigned short u16x4 __attribute__((ext_vector_type(4)));
typedef unsigned short us;

__device__ __forceinline__ us f2bf(float f) {
    unsigned u = __builtin_bit_cast(unsigned, f);
    u += 0x7FFFu + ((u >> 16) & 1u);
    return (us)(u >> 16);
}

__device__ __forceinline__ unsigned pack2(float lo, float hi) {
    return (unsigned)f2bf(lo) | ((unsigned)f2bf(hi) << 16);
}

__device__ __forceinline__ float bf2f(us v) {
    unsigned u = ((unsigned)v) << 16;
    return __builtin_bit_cast(float, u);
}

__device__ __forceinline__ bf16x8 ld_bf8(const us* p) {
    return __builtin_bit_cast(bf16x8, *reinterpret_cast<const u32x4*>(p));
}

__device__ __forceinline__ void gld_lds16(const us* g, us* l) {
    __builtin_amdgcn_global_load_lds(
        (const __attribute__((address_space(1))) unsigned int*)g,
        (__attribute__((address_space(3))) unsigned int*)l, 16, 0, 0);
}

// ---------------- weights-only convert -------------------------------------
__launch_bounds__(256)
__global__ void cvt_w(const float* __restrict__ w_in, const float* __restrict__ w_out,
                      us* __restrict__ Wb, us* __restrict__ WOb)
{
    const int bid = blockIdx.x;
    const int tid = threadIdx.x;
    if (bid < 960) {
        int i = bid * 256 + tid;
        f32x4 a = reinterpret_cast<const f32x4*>(w_in)[i];
        u16x4 r;
#pragma unroll
        for (int j = 0; j < 4; ++j) r[j] = f2bf(a[j]);
        reinterpret_cast<u16x4*>(Wb)[i] = r;
    } else {
        int i = (bid - 960) * 256 + tid;
        f32x4 a = reinterpret_cast<const f32x4*>(w_out)[i];
        u16x4 r;
#pragma unroll
        for (int j = 0; j < 4; ++j) r[j] = f2bf(a[j]);
        reinterpret_cast<u16x4*>(WOb)[i] = r;
    }
}

// ---------------- fused-convert QKV GEMM -----------------------------------
// C[M,256] = bf16(a1 (+a2))[M,256] * W[256,256]^T, 128x128 tile, BK=64,
// double-buffered. A: f32 global loads -> reg convert -> ds_write_b128
// (issued after compute so load latency is hidden). W: global_load_lds.
// Transposed mfma(bf,af); epilogue mi-outer/ni-inner -> full 64B sectors.
template <bool TWO>
__device__ __forceinline__ void gemm_f32_body(
    const float* __restrict__ a1, const float* __restrict__ a2,
    const us* __restrict__ Wg, const float* __restrict__ bias,
    us* __restrict__ Cout, float scale, int M)
{
    const int row0 = blockIdx.x * 128;
    const int col0 = blockIdx.y * 128;
    __shared__ us As[2 * 8192];
    __shared__ us Bs[2 * 8192];
    const int tid  = threadIdx.x;
    const int lane = tid & 63;
    const int w    = tid >> 6;
    const int l15  = lane & 15;
    const int quad = lane >> 4;
    const int wm   = (w >> 1) * 64;
    const int wn   = (w & 1) * 64;
    const int srow = lane >> 3;
    const int gofs = ((lane & 7) ^ srow) * 8;

    f32x4 P[4][2], Q2[4][2];

    auto loadA = [&](int kt) {
#pragma unroll
        for (int cc = 0; cc < 4; ++cc) {
            const int c = w * 4 + cc;
            const int row = c * 8 + srow;
            const int gr = (row0 + row < M) ? (row0 + row) : (M - 1);  // clamp: no OOB
            const float* p = a1 + (size_t)gr * 256 + kt * 64 + gofs;
            P[cc][0] = *reinterpret_cast<const f32x4*>(p);
            P[cc][1] = *reinterpret_cast<const f32x4*>(p + 4);
            if constexpr (TWO) {
                const float* q = a2 + (size_t)gr * 256 + kt * 64 + gofs;
                Q2[cc][0] = *reinterpret_cast<const f32x4*>(q);
                Q2[cc][1] = *reinterpret_cast<const f32x4*>(q + 4);
            }
        }
    };
    auto writeA = [&](int buf) {
#pragma unroll
        for (int cc = 0; cc < 4; ++cc) {
            const int c = w * 4 + cc;
            f32x4 e0 = P[cc][0], e1 = P[cc][1];
            if constexpr (TWO) { e0 += Q2[cc][0]; e1 += Q2[cc][1]; }
            u32x4 pk;
            pk[0] = pack2(e0[0], e0[1]);
            pk[1] = pack2(e0[2], e0[3]);
            pk[2] = pack2(e1[0], e1[1]);
            pk[3] = pack2(e1[2], e1[3]);
            *reinterpret_cast<u32x4*>(&As[buf * 8192 + c * 512 + lane * 8]) = pk;
        }
    };
    auto loadW = [&](int buf, int kt) {
#pragma unroll
        for (int cc = 0; cc < 4; ++cc) {
            const int c = w * 4 + cc;
            const int row = c * 8 + srow;
            gld_lds16(Wg + (size_t)(col0 + row) * 256 + kt * 64 + gofs,
                      &Bs[buf * 8192 + c * 512]);
        }
    };

    // prologue: tile 0
    loadA(0);
    loadW(0, 0);
    writeA(0);
    __syncthreads();

    f32x4 acc[4][4] = {};

#pragma unroll
    for (int kt = 0; kt < 4; ++kt) {
        const int cur = kt & 1;
        if (kt < 3) {            // issue next tile's loads before compute
            loadA(kt + 1);
            loadW(cur ^ 1, kt + 1);
        }
#pragma unroll
        for (int kh = 0; kh < 2; ++kh) {
            bf16x8 af[4], bf[4];
#pragma unroll
            for (int mi = 0; mi < 4; ++mi) {
                const int row = wm + mi * 16 + l15;
                const int seg = (kh * 4 + quad) ^ (row & 7);
                af[mi] = ld_bf8(&As[cur * 8192 + row * 64 + seg * 8]);
            }
#pragma unroll
            for (int ni = 0; ni < 4; ++ni) {
                const int col = wn + ni * 16 + l15;
                const int seg = (kh * 4 + quad) ^ (col & 7);
                bf[ni] = ld_bf8(&Bs[cur * 8192 + col * 64 + seg * 8]);
            }
#pragma unroll
            for (int mi = 0; mi < 4; ++mi)
#pragma unroll
                for (int ni = 0; ni < 4; ++ni)
                    acc[mi][ni] = __builtin_amdgcn_mfma_f32_16x16x32_bf16(bf[ni], af[mi], acc[mi][ni], 0, 0, 0);
        }
        if (kt < 3) {
            writeA(cur ^ 1);     // loads had the whole compute phase to land
            __syncthreads();
        }
    }

    // epilogue: mi-outer, ni-inner -> each row's 128B written back-to-back
#pragma unroll
    for (int mi = 0; mi < 4; ++mi) {
        const int row = row0 + wm + mi * 16 + l15;
        if (row < M) {
            us* cp = Cout + (size_t)row * 256;
#pragma unroll
            for (int ni = 0; ni < 4; ++ni) {
                const int colb = col0 + wn + ni * 16 + quad * 4;
                const f32x4 b4 = *reinterpret_cast<const f32x4*>(bias + colb);
                u32x2 pk;
                pk[0] = pack2((acc[mi][ni][0] + b4[0]) * scale,
                              (acc[mi][ni][1] + b4[1]) * scale);
                pk[1] = pack2((acc[mi][ni][2] + b4[2]) * scale,
                              (acc[mi][ni][3] + b4[3]) * scale);
                *reinterpret_cast<u32x2*>(cp + colb) = pk;
            }
        }
    }
}

// z 0..4 = Q (x<13), 5..9 = K, 10..14 = V
__launch_bounds__(256, 2)
__global__ void gemm_qkv(const float* __restrict__ tgt, const float* __restrict__ qpos,
                         const float* __restrict__ mem, const float* __restrict__ pos,
                         const us* __restrict__ Wb, const float* __restrict__ b_in,
                         us* __restrict__ Qb, us* __restrict__ Kb, us* __restrict__ Vb)
{
    const int z = blockIdx.z;
    if (z < 5) {
        if (blockIdx.x >= 13) return;
        gemm_f32_body<true>(tgt, qpos, Wb + (size_t)z * 196608, b_in + (size_t)z * 768,
                            Qb + (size_t)z * 409600, 0.17677669529663687f, 1600);
    } else if (z < 10) {
        const int e = z - 5;
        gemm_f32_body<true>(mem, pos, Wb + 65536 + (size_t)e * 196608,
                            b_in + (size_t)e * 768 + 256,
                            Kb + (size_t)e * 4194304, 1.0f, 16384);
    } else {
        const int e = z - 10;
        gemm_f32_body<false>(mem, nullptr, Wb + 131072 + (size_t)e * 196608,
                             b_in + (size_t)e * 768 + 512,
                             Vb + (size_t)e * 4194304, 1.0f, 16384);
    }
}

// ---------------- out-proj GEMM (bf16 A via gld_lds, R6 pattern) -----------
__launch_bounds__(256)
__global__ void gemm_o(const us* __restrict__ CTXall, const us* __restrict__ WOall,
                       const float* __restrict__ b_out, float* __restrict__ OUTall)
{
    const int e = blockIdx.z;
    const us* A = CTXall + (size_t)e * 409600;
    const us* W = WOall + (size_t)e * 65536;
    const float* bias = b_out + (size_t)e * 256;
    float* Cout = OUTall + (size_t)e * 409600;
    const int M = 1600;

    const int row0 = blockIdx.x * 128;
    const int col0 = blockIdx.y * 128;
    __shared__ us As[2 * 8192];
    __shared__ us Bs[2 * 8192];
    const int tid  = threadIdx.x;
    const int lane = tid & 63;
    const int w    = tid >> 6;
    const int l15  = lane & 15;
    const int quad = lane >> 4;
    const int wm   = (w >> 1) * 64;
    const int wn   = (w & 1) * 64;
    const int srow = lane >> 3;
    const int gofs = ((lane & 7) ^ srow) * 8;

#pragma unroll
    for (int cc = 0; cc < 4; ++cc) {
        const int c = w * 4 + cc;
        const int row = c * 8 + srow;
        gld_lds16(A + (size_t)(row0 + row) * 256 + gofs, &As[c * 512]);
        gld_lds16(W + (size_t)(col0 + row) * 256 + gofs, &Bs[c * 512]);
    }
    __syncthreads();

    f32x4 acc[4][4] = {};

#pragma unroll
    for (int kt = 0; kt < 4; ++kt) {
        const int cur = (kt & 1) * 8192;
        if (kt < 3) {
            const int nxt = ((kt + 1) & 1) * 8192;
            const int k0 = (kt + 1) * 64;
#pragma unroll
            for (int cc = 0; cc < 4; ++cc) {
                const int c = w * 4 + cc;
                const int row = c * 8 + srow;
                gld_lds16(A + (size_t)(row0 + row) * 256 + k0 + gofs, &As[nxt + c * 512]);
                gld_lds16(W + (size_t)(col0 + row) * 256 + k0 + gofs, &Bs[nxt + c * 512]);
            }
        }
#pragma unroll
        for (int kh = 0; kh < 2; ++kh) {
            bf16x8 af[4], bf[4];
#pragma unroll
            for (int mi = 0; mi < 4; ++mi) {
                const int row = wm + mi * 16 + l15;
                const int seg = (kh * 4 + quad) ^ (row & 7);
                af[mi] = ld_bf8(&As[cur + row * 64 + seg * 8]);
            }
#pragma unroll
            for (int ni = 0; ni < 4; ++ni) {
                const int col = wn + ni * 16 + l15;
                const int seg = (kh * 4 + quad) ^ (col & 7);
                bf[ni] = ld_bf8(&Bs[cur + col * 64 + seg * 8]);
            }
#pragma unroll
            for (int mi = 0; mi < 4; ++mi)
#pragma unroll
                for (int ni = 0; ni < 4; ++ni)
                    acc[mi][ni] = __builtin_amdgcn_mfma_f32_16x16x32_bf16(bf[ni], af[mi], acc[mi][ni], 0, 0, 0);
        }
        if (kt < 3) __syncthreads();
    }

#pragma unroll
    for (int mi = 0; mi < 4; ++mi) {
        const int row = row0 + wm + mi * 16 + l15;
        if (row < M) {
#pragma unroll
            for (int ni = 0; ni < 4; ++ni) {
                const int colb = col0 + wn + ni * 16 + quad * 4;
                const f32x4 b4 = *reinterpret_cast<const f32x4*>(bias + colb);
                f32x4 v;
#pragma unroll
                for (int r = 0; r < 4; ++r) v[r] = acc[mi][ni][r] + b4[r];
                *reinterpret_cast<f32x4*>(Cout + (size_t)row * 256 + colb) = v;
            }
        }
    }
}

// ---------------- split-K attention (unchanged from R4) --------------------
__device__ __forceinline__ int vrow(int d) { return d * 264 + 8 * (d >> 3); }

__launch_bounds__(512)
__global__ void attn(const us* __restrict__ Qb, const us* __restrict__ Kb,
                     const us* __restrict__ Vb, us* __restrict__ PO,
                     float* __restrict__ PL)
{
    const int h = blockIdx.x;
    const int z = blockIdx.y;
    const int s = blockIdx.z;
    const int e = z >> 4, b = z & 15;
    const int tid  = threadIdx.x;
    const int w    = tid >> 6;
    const int lane = tid & 63;
    const int l15  = lane & 15, quad = lane >> 4;
    __shared__ us Ks[256 * 32];
    __shared__ us Vs[8464];
    __shared__ us Ps[7][16 * 40];

    const int key0 = s * 256;
    {
        const int kl  = lane >> 2;
        const int seg = lane & 3;
        const us* kg = Kb + ((size_t)((e * 1024 + key0 + w * 16 + kl) * 16 + b)) * 256
                          + h * 32 + seg * 8;
        gld_lds16(kg, &Ks[w * 512]);
        gld_lds16(kg + (size_t)128 * 16 * 256, &Ks[4096 + w * 512]);

        const int kv = tid >> 2;
        const int sg = tid & 3;
        const us* vg = Vb + ((size_t)((e * 1024 + key0 + kv) * 16 + b)) * 256
                          + h * 32 + sg * 8;
        u32x4 v0 = *reinterpret_cast<const u32x4*>(vg);
        u32x4 v1 = *reinterpret_cast<const u32x4*>(vg + (size_t)128 * 16 * 256);
#pragma unroll
        for (int j = 0; j < 4; ++j) {
            const int d0 = sg * 8 + 2 * j;
            const int e0 = vrow(d0);
            const int e1 = e0 + 264;
            Vs[e0 + kv]       = (us)(v0[j] & 0xffff);
            Vs[e1 + kv]       = (us)(v0[j] >> 16);
            Vs[e0 + 128 + kv] = (us)(v1[j] & 0xffff);
            Vs[e1 + 128 + kv] = (us)(v1[j] >> 16);
        }
    }
    u32x4 qraw = {0u, 0u, 0u, 0u};
    if (w < 7) {
        const int l = w * 16 + l15;
        if (l < 100)
            qraw = *reinterpret_cast<const u32x4*>(
                Qb + ((size_t)((e * 100 + l) * 16 + b)) * 256 + h * 32 + quad * 8);
    }
    const bf16x8 qf = __builtin_bit_cast(bf16x8, qraw);

    __syncthreads();

    if (w >= 7) return;

    const f32x4 zacc = {};
    f32x4 o0 = {}, o1 = {};
    float lsum = 0.0f;

    for (int c = 0; c < 8; ++c) {
        bf16x8 kf0 = ld_bf8(&Ks[(c * 32 + l15) * 32 + quad * 8]);
        bf16x8 kf1 = ld_bf8(&Ks[(c * 32 + 16 + l15) * 32 + quad * 8]);
        f32x4 s0 = __builtin_amdgcn_mfma_f32_16x16x32_bf16(kf0, qf, zacc, 0, 0, 0);
        f32x4 s1 = __builtin_amdgcn_mfma_f32_16x16x32_bf16(kf1, qf, zacc, 0, 0, 0);
        float p0[4], p1[4];
#pragma unroll
        for (int r = 0; r < 4; ++r) {
            p0[r] = __expf(s0[r]);
            p1[r] = __expf(s1[r]);
            lsum += p0[r] + p1[r];
        }
        u32x2 w0, w1;
        w0[0] = pack2(p0[0], p0[1]);
        w0[1] = pack2(p0[2], p0[3]);
        w1[0] = pack2(p1[0], p1[1]);
        w1[1] = pack2(p1[2], p1[3]);
        *reinterpret_cast<u32x2*>(&Ps[w][l15 * 40 + quad * 4])      = w0;
        *reinterpret_cast<u32x2*>(&Ps[w][l15 * 40 + 16 + quad * 4]) = w1;
        bf16x8 pf  = ld_bf8(&Ps[w][l15 * 40 + quad * 8]);
        bf16x8 vf0 = ld_bf8(&Vs[vrow(l15) + c * 32 + quad * 8]);
        bf16x8 vf1 = ld_bf8(&Vs[vrow(16 + l15) + c * 32 + quad * 8]);
        o0 = __builtin_amdgcn_mfma_f32_16x16x32_bf16(pf, vf0, o0, 0, 0, 0);
        o1 = __builtin_amdgcn_mfma_f32_16x16x32_bf16(pf, vf1, o1, 0, 0, 0);
    }

    lsum += __shfl_xor(lsum, 16, 64);
    lsum += __shfl_xor(lsum, 32, 64);

#pragma unroll
    for (int r = 0; r < 4; ++r) {
        const int row = w * 16 + quad * 4 + r;
        if (row < 100) {
            const size_t o = (((size_t)((s * 5 + e) * 100 + row)) * 16 + b) * 256 + h * 32;
            PO[o + l15]      = f2bf(o0[r]);
            PO[o + 16 + l15] = f2bf(o1[r]);
        }
    }
    const int q = w * 16 + l15;
    if (quad == 0 && q < 100)
        PL[((((size_t)s * 5 + e) * 16 + b) * 8 + h) * 128 + q] = lsum;
}

// ---------------- combine partials -> CTX bf16 -----------------------------
__launch_bounds__(256)
__global__ void combine(const us* __restrict__ PO, const float* __restrict__ PL,
                        us* __restrict__ CTX)
{
    const int blk = blockIdx.x;
    const int e   = blk / 1600;
    const int rem = blk - e * 1600;
    const int row = rem >> 4;
    const int b   = rem & 15;
    const int d   = threadIdx.x;
    const int h   = d >> 5;
    float O = 0.0f, L = 0.0f;
#pragma unroll
    for (int s = 0; s < 4; ++s) {
        O += bf2f(PO[(((size_t)((s * 5 + e) * 100 + row)) * 16 + b) * 256 + d]);
        L += PL[((((size_t)s * 5 + e) * 16 + b) * 8 + h) * 128 + row];
    }
    CTX[(((size_t)(e * 100 + row)) * 16 + b) * 256 + d] = f2bf(O / L);
}

// ---------------- gate + mix + residual + LayerNorm ------------------------
__launch_bounds__(256)
__global__ void finalize(const float* __restrict__ tgt, const float* __restrict__ w_gate,
                         const float* __restrict__ b_gate, const float* __restrict__ OUTf,
                         const float* __restrict__ gamma, const float* __restrict__ beta,
                         float* __restrict__ out)
{
    const int row = blockIdx.x;
    const int d = threadIdx.x;
    __shared__ float red[4];
    const float t = tgt[(size_t)row * 256 + d];

    float g[5];
#pragma unroll
    for (int e = 0; e < 5; ++e) {
        float part = t * w_gate[e * 256 + d];
#pragma unroll
        for (int off = 32; off >= 1; off >>= 1) part += __shfl_xor(part, off, 64);
        if ((d & 63) == 0) red[d >> 6] = part;
        __syncthreads();
        g[e] = red[0] + red[1] + red[2] + red[3] + b_gate[e];
        __syncthreads();
    }
    float mx = g[0];
#pragma unroll
    for (int e = 1; e < 5; ++e) mx = fmaxf(mx, g[e]);
    float sm = 0.0f;
#pragma unroll
    for (int e = 0; e < 5; ++e) { g[e] = __expf(g[e] - mx); sm += g[e]; }
    const float invs = 1.0f / sm;

    float mo = 0.0f;
#pragma unroll
    for (int e = 0; e < 5; ++e)
        mo += g[e] * invs * OUTf[((size_t)e * 1600 + row) * 256 + d];
    const float x = t + mo;

    float part = x;
#pragma unroll
    for (int off = 32; off >= 1; off >>= 1) part += __shfl_xor(part, off, 64);
    if ((d & 63) == 0) red[d >> 6] = part;
    __syncthreads();
    const float mean = (red[0] + red[1] + red[2] + red[3]) * (1.0f / 256.0f);
    __syncthreads();

    const float diff = x - mean;
    part = diff * diff;
#pragma unroll
    for (int off = 32; off >= 1; off >>= 1) part += __shfl_xor(part, off, 64);
    if ((d & 63) == 0) red[d >> 6] = part;
    __syncthreads();
    const float var = (red[0] + red[1] + red[2] + red[3]) * (1.0f / 256.0f);

    out[(size_t)row * 256 + d] = diff * rsqrtf(var + 1e-5f) * gamma[d] + beta[d];
}

// ---------------------------------------------------------------------------
extern "C" void kernel_launch(void* const* d_in, const int* in_sizes, int n_in,
                              void* d_out, int out_size, void* d_ws, size_t ws_size,
                              hipStream_t stream)
{
    const float* tgt    = (const float*)d_in[0];
    const float* mem    = (const float*)d_in[1];
    const float* qpos   = (const float*)d_in[2];
    const float* pos    = (const float*)d_in[3];
    const float* w_in   = (const float*)d_in[4];
    const float* b_in   = (const float*)d_in[5];
    const float* w_out  = (const float*)d_in[6];
    const float* b_out  = (const float*)d_in[7];
    const float* w_gate = (const float*)d_in[8];
    const float* b_gate = (const float*)d_in[9];
    const float* ln_g   = (const float*)d_in[10];
    const float* ln_b   = (const float*)d_in[11];
    float* out = (float*)d_out;

    char* p = (char*)d_ws;
    auto alloc = [&](size_t n) { char* r = p; p += (n + 255) & ~(size_t)255; return r; };

    us* Wb   = (us*)alloc(983040ull * 2);
    us* WOb  = (us*)alloc(327680ull * 2);
    us* Qb   = (us*)alloc(5ull * 409600 * 2);
    us* Kb   = (us*)alloc(5ull * 4194304 * 2);
    us* Vb   = (us*)alloc(5ull * 4194304 * 2);
    us* CTXb = (us*)alloc(5ull * 409600 * 2);
    float* OUTf = (float*)alloc(5ull * 409600 * 4);
    us*    PO = (us*)alloc(4ull * 5 * 409600 * 2);    // [s][e][l][b][d] bf16
    float* PL = (float*)alloc(4ull * 5 * 16 * 8 * 128 * 4);

    cvt_w<<<1280, 256, 0, stream>>>(w_in, w_out, Wb, WOb);

    gemm_qkv<<<dim3(128, 2, 15), 256, 0, stream>>>(
        tgt, qpos, mem, pos, Wb, b_in, Qb, Kb, Vb);

    attn<<<dim3(8, 80, 4), 512, 0, stream>>>(Qb, Kb, Vb, PO, PL);

    combine<<<8000, 256, 0, stream>>>(PO, PL, CTXb);

    gemm_o<<<dim3(13, 2, 5), 256, 0, stream>>>(CTXb, WOb, b_out, OUTf);

    finalize<<<1600, 256, 0, stream>>>(tgt, w_gate, b_gate, OUTf, ln_g, ln_b, out);
}

// Round 8
// 213.136 us; speedup vs baseline: 1.2366x; 1.2366x over previous
//
#include <hip/hip_runtime.h>

// ---------------------------------------------------------------------------
// MoE cross-attention decoder layer on MI355X (gfx950), bf16 MFMA pipeline.
// R8: R5 pipeline (cvt_all -> gemm_qkv[bf16 A, gld_lds, dbuf] -> split-K attn
// -> combine -> gemm_o -> finalize) with ONE change: GEMM epilogue is
// mi-outer / ni-inner so both 32B halves of each 64B L2 sector are written
// back-to-back (R6/R7-verified WRITE_SIZE fix, 155->86 MB).
// ---------------------------------------------------------------------------

typedef __bf16 bf16x8 __attribute__((ext_vector_type(8)));
typedef float f32x4 __attribute__((ext_vector_type(4)));
typedef unsigned int u32x4 __attribute__((ext_vector_type(4)));
typedef unsigned int u32x2 __attribute__((ext_vector_type(2)));
typedef unsigned short u16x4 __attribute__((ext_vector_type(4)));
typedef unsigned short us;

__device__ __forceinline__ us f2bf(float f) {
    unsigned u = __builtin_bit_cast(unsigned, f);
    u += 0x7FFFu + ((u >> 16) & 1u);
    return (us)(u >> 16);
}

__device__ __forceinline__ unsigned pack2(float lo, float hi) {
    return (unsigned)f2bf(lo) | ((unsigned)f2bf(hi) << 16);
}

__device__ __forceinline__ float bf2f(us v) {
    unsigned u = ((unsigned)v) << 16;
    return __builtin_bit_cast(float, u);
}

__device__ __forceinline__ bf16x8 ld_bf8(const us* p) {
    return __builtin_bit_cast(bf16x8, *reinterpret_cast<const u32x4*>(p));
}

__device__ __forceinline__ void gld_lds16(const us* g, us* l) {
    __builtin_amdgcn_global_load_lds(
        (const __attribute__((address_space(1))) unsigned int*)g,
        (__attribute__((address_space(3))) unsigned int*)l, 16, 0, 0);
}

// ---------------- fused converts: one launch -------------------------------
__launch_bounds__(256)
__global__ void cvt_all(const float* __restrict__ tgt, const float* __restrict__ qpos,
                        const float* __restrict__ mem, const float* __restrict__ pos,
                        const float* __restrict__ w_in, const float* __restrict__ w_out,
                        us* __restrict__ Aq, us* __restrict__ Ak, us* __restrict__ Av,
                        us* __restrict__ Wb, us* __restrict__ WOb)
{
    const int bid = blockIdx.x;
    const int tid = threadIdx.x;
    if (bid < 400) {
        int i = bid * 256 + tid;
        f32x4 a = reinterpret_cast<const f32x4*>(tgt)[i];
        f32x4 b = reinterpret_cast<const f32x4*>(qpos)[i];
        u16x4 r;
#pragma unroll
        for (int j = 0; j < 4; ++j) r[j] = f2bf(a[j] + b[j]);
        reinterpret_cast<u16x4*>(Aq)[i] = r;
    } else if (bid < 4496) {
        int i = (bid - 400) * 256 + tid;
        f32x4 m = reinterpret_cast<const f32x4*>(mem)[i];
        f32x4 p = reinterpret_cast<const f32x4*>(pos)[i];
        u16x4 rk, rv;
#pragma unroll
        for (int j = 0; j < 4; ++j) { rk[j] = f2bf(m[j] + p[j]); rv[j] = f2bf(m[j]); }
        reinterpret_cast<u16x4*>(Ak)[i] = rk;
        reinterpret_cast<u16x4*>(Av)[i] = rv;
    } else if (bid < 5456) {
        int i = (bid - 4496) * 256 + tid;
        f32x4 a = reinterpret_cast<const f32x4*>(w_in)[i];
        u16x4 r;
#pragma unroll
        for (int j = 0; j < 4; ++j) r[j] = f2bf(a[j]);
        reinterpret_cast<u16x4*>(Wb)[i] = r;
    } else {
        int i = (bid - 5456) * 256 + tid;
        f32x4 a = reinterpret_cast<const f32x4*>(w_out)[i];
        u16x4 r;
#pragma unroll
        for (int j = 0; j < 4; ++j) r[j] = f2bf(a[j]);
        reinterpret_cast<u16x4*>(WOb)[i] = r;
    }
}

// ---------------- GEMM body: C[M,256] = A[M,256] * W[256,256]^T ------------
// 128x128 tile, BK=64, double-buffered global_load_lds (16B), xor swizzle.
// Transposed mfma(bf, af): lane l15 = output row, quad*4+r = 4 consecutive
// output cols. Epilogue mi-outer/ni-inner: full 64B sectors per row.
template <bool BF16OUT>
__device__ __forceinline__ void gemm_body(const us* __restrict__ A,
                                          const us* __restrict__ W,
                                          const float* __restrict__ bias,
                                          void* __restrict__ Cout,
                                          float scale, int M)
{
    const int row0 = blockIdx.x * 128;
    const int col0 = blockIdx.y * 128;
    __shared__ us As[2 * 8192];   // 2 x 16KB
    __shared__ us Bs[2 * 8192];
    const int tid  = threadIdx.x;
    const int lane = tid & 63;
    const int w    = tid >> 6;
    const int l15  = lane & 15;
    const int quad = lane >> 4;
    const int wm   = (w >> 1) * 64;
    const int wn   = (w & 1) * 64;
    const int srow = lane >> 3;
    const int gofs = ((lane & 7) ^ srow) * 8;

    // prologue: stage tile 0 into buffer 0
#pragma unroll
    for (int cc = 0; cc < 4; ++cc) {
        const int c = w * 4 + cc;
        const int row = c * 8 + srow;
        gld_lds16(A + (size_t)(row0 + row) * 256 + gofs, &As[c * 512]);
        gld_lds16(W + (size_t)(col0 + row) * 256 + gofs, &Bs[c * 512]);
    }
    __syncthreads();

    f32x4 acc[4][4] = {};

#pragma unroll
    for (int kt = 0; kt < 4; ++kt) {
        const int cur = (kt & 1) * 8192;
        if (kt < 3) {  // prefetch next tile into other buffer (issued pre-compute)
            const int nxt = ((kt + 1) & 1) * 8192;
            const int k0 = (kt + 1) * 64;
#pragma unroll
            for (int cc = 0; cc < 4; ++cc) {
                const int c = w * 4 + cc;
                const int row = c * 8 + srow;
                gld_lds16(A + (size_t)(row0 + row) * 256 + k0 + gofs, &As[nxt + c * 512]);
                gld_lds16(W + (size_t)(col0 + row) * 256 + k0 + gofs, &Bs[nxt + c * 512]);
            }
        }
#pragma unroll
        for (int kh = 0; kh < 2; ++kh) {
            bf16x8 af[4], bf[4];
#pragma unroll
            for (int mi = 0; mi < 4; ++mi) {
                const int row = wm + mi * 16 + l15;
                const int seg = (kh * 4 + quad) ^ (row & 7);
                af[mi] = ld_bf8(&As[cur + row * 64 + seg * 8]);
            }
#pragma unroll
            for (int ni = 0; ni < 4; ++ni) {
                const int col = wn + ni * 16 + l15;
                const int seg = (kh * 4 + quad) ^ (col & 7);
                bf[ni] = ld_bf8(&Bs[cur + col * 64 + seg * 8]);
            }
#pragma unroll
            for (int mi = 0; mi < 4; ++mi)
#pragma unroll
                for (int ni = 0; ni < 4; ++ni)  // transposed: row<-af(l15), col<-bf(quad*4+r)
                    acc[mi][ni] = __builtin_amdgcn_mfma_f32_16x16x32_bf16(bf[ni], af[mi], acc[mi][ni], 0, 0, 0);
        }
        if (kt < 3) __syncthreads();  // drain prefetch (overlapped by compute) + WAR
    }

    // epilogue: mi-outer, ni-inner -> each row's 4x32B written back-to-back
#pragma unroll
    for (int mi = 0; mi < 4; ++mi) {
        const int row = row0 + wm + mi * 16 + l15;
        if (row < M) {
#pragma unroll
            for (int ni = 0; ni < 4; ++ni) {
                const int colb = col0 + wn + ni * 16 + quad * 4;
                const f32x4 b4 = *reinterpret_cast<const f32x4*>(bias + colb);
                if constexpr (BF16OUT) {
                    u32x2 pk;
                    pk[0] = pack2((acc[mi][ni][0] + b4[0]) * scale,
                                  (acc[mi][ni][1] + b4[1]) * scale);
                    pk[1] = pack2((acc[mi][ni][2] + b4[2]) * scale,
                                  (acc[mi][ni][3] + b4[3]) * scale);
                    *reinterpret_cast<u32x2*>(reinterpret_cast<us*>(Cout) + (size_t)row * 256 + colb) = pk;
                } else {
                    f32x4 v;
#pragma unroll
                    for (int r = 0; r < 4; ++r) v[r] = (acc[mi][ni][r] + b4[r]) * scale;
                    *reinterpret_cast<f32x4*>(reinterpret_cast<float*>(Cout) + (size_t)row * 256 + colb) = v;
                }
            }
        }
    }
}

// merged Q/K/V projection: z 0..4 = Q (x<13), 5..9 = K, 10..14 = V
__launch_bounds__(256)
__global__ void gemm_qkv(const us* __restrict__ Aq, const us* __restrict__ Ak,
                         const us* __restrict__ Av, const us* __restrict__ Wb,
                         const float* __restrict__ b_in,
                         us* __restrict__ Qb, us* __restrict__ Kb, us* __restrict__ Vb)
{
    const int z = blockIdx.z;
    if (z < 5) {
        if (blockIdx.x >= 13) return;
        gemm_body<true>(Aq, Wb + (size_t)z * 196608, b_in + (size_t)z * 768,
                        Qb + (size_t)z * 409600, 0.17677669529663687f, 1600);
    } else if (z < 10) {
        const int e = z - 5;
        gemm_body<true>(Ak, Wb + 65536 + (size_t)e * 196608, b_in + (size_t)e * 768 + 256,
                        Kb + (size_t)e * 4194304, 1.0f, 16384);
    } else {
        const int e = z - 10;
        gemm_body<true>(Av, Wb + 131072 + (size_t)e * 196608, b_in + (size_t)e * 768 + 512,
                        Vb + (size_t)e * 4194304, 1.0f, 16384);
    }
}

__launch_bounds__(256)
__global__ void gemm_o(const us* __restrict__ CTXb, const us* __restrict__ WOb,
                       const float* __restrict__ b_out, float* __restrict__ OUTf)
{
    const int e = blockIdx.z;
    gemm_body<false>(CTXb + (size_t)e * 409600, WOb + (size_t)e * 65536,
                     b_out + (size_t)e * 256, OUTf + (size_t)e * 409600, 1.0f, 1600);
}

// ---------------- split-K attention (unchanged from R4) --------------------
__device__ __forceinline__ int vrow(int d) { return d * 264 + 8 * (d >> 3); }

__launch_bounds__(512)
__global__ void attn(const us* __restrict__ Qb, const us* __restrict__ Kb,
                     const us* __restrict__ Vb, us* __restrict__ PO,
                     float* __restrict__ PL)
{
    const int h = blockIdx.x;
    const int z = blockIdx.y;
    const int s = blockIdx.z;
    const int e = z >> 4, b = z & 15;
    const int tid  = threadIdx.x;
    const int w    = tid >> 6;
    const int lane = tid & 63;
    const int l15  = lane & 15, quad = lane >> 4;
    __shared__ us Ks[256 * 32];
    __shared__ us Vs[8464];
    __shared__ us Ps[7][16 * 40];

    const int key0 = s * 256;
    {
        const int kl  = lane >> 2;
        const int seg = lane & 3;
        const us* kg = Kb + ((size_t)((e * 1024 + key0 + w * 16 + kl) * 16 + b)) * 256
                          + h * 32 + seg * 8;
        gld_lds16(kg, &Ks[w * 512]);
        gld_lds16(kg + (size_t)128 * 16 * 256, &Ks[4096 + w * 512]);

        const int kv = tid >> 2;
        const int sg = tid & 3;
        const us* vg = Vb + ((size_t)((e * 1024 + key0 + kv) * 16 + b)) * 256
                          + h * 32 + sg * 8;
        u32x4 v0 = *reinterpret_cast<const u32x4*>(vg);
        u32x4 v1 = *reinterpret_cast<const u32x4*>(vg + (size_t)128 * 16 * 256);
#pragma unroll
        for (int j = 0; j < 4; ++j) {
            const int d0 = sg * 8 + 2 * j;
            const int e0 = vrow(d0);
            const int e1 = e0 + 264;
            Vs[e0 + kv]       = (us)(v0[j] & 0xffff);
            Vs[e1 + kv]       = (us)(v0[j] >> 16);
            Vs[e0 + 128 + kv] = (us)(v1[j] & 0xffff);
            Vs[e1 + 128 + kv] = (us)(v1[j] >> 16);
        }
    }
    u32x4 qraw = {0u, 0u, 0u, 0u};
    if (w < 7) {
        const int l = w * 16 + l15;
        if (l < 100)
            qraw = *reinterpret_cast<const u32x4*>(
                Qb + ((size_t)((e * 100 + l) * 16 + b)) * 256 + h * 32 + quad * 8);
    }
    const bf16x8 qf = __builtin_bit_cast(bf16x8, qraw);

    __syncthreads();

    if (w >= 7) return;

    const f32x4 zacc = {};
    f32x4 o0 = {}, o1 = {};
    float lsum = 0.0f;

    for (int c = 0; c < 8; ++c) {
        bf16x8 kf0 = ld_bf8(&Ks[(c * 32 + l15) * 32 + quad * 8]);
        bf16x8 kf1 = ld_bf8(&Ks[(c * 32 + 16 + l15) * 32 + quad * 8]);
        f32x4 s0 = __builtin_amdgcn_mfma_f32_16x16x32_bf16(kf0, qf, zacc, 0, 0, 0);
        f32x4 s1 = __builtin_amdgcn_mfma_f32_16x16x32_bf16(kf1, qf, zacc, 0, 0, 0);
        float p0[4], p1[4];
#pragma unroll
        for (int r = 0; r < 4; ++r) {
            p0[r] = __expf(s0[r]);
            p1[r] = __expf(s1[r]);
            lsum += p0[r] + p1[r];
        }
        u32x2 w0, w1;
        w0[0] = pack2(p0[0], p0[1]);
        w0[1] = pack2(p0[2], p0[3]);
        w1[0] = pack2(p1[0], p1[1]);
        w1[1] = pack2(p1[2], p1[3]);
        *reinterpret_cast<u32x2*>(&Ps[w][l15 * 40 + quad * 4])      = w0;
        *reinterpret_cast<u32x2*>(&Ps[w][l15 * 40 + 16 + quad * 4]) = w1;
        bf16x8 pf  = ld_bf8(&Ps[w][l15 * 40 + quad * 8]);
        bf16x8 vf0 = ld_bf8(&Vs[vrow(l15) + c * 32 + quad * 8]);
        bf16x8 vf1 = ld_bf8(&Vs[vrow(16 + l15) + c * 32 + quad * 8]);
        o0 = __builtin_amdgcn_mfma_f32_16x16x32_bf16(pf, vf0, o0, 0, 0, 0);
        o1 = __builtin_amdgcn_mfma_f32_16x16x32_bf16(pf, vf1, o1, 0, 0, 0);
    }

    lsum += __shfl_xor(lsum, 16, 64);
    lsum += __shfl_xor(lsum, 32, 64);

#pragma unroll
    for (int r = 0; r < 4; ++r) {
        const int row = w * 16 + quad * 4 + r;
        if (row < 100) {
            const size_t o = (((size_t)((s * 5 + e) * 100 + row)) * 16 + b) * 256 + h * 32;
            PO[o + l15]      = f2bf(o0[r]);
            PO[o + 16 + l15] = f2bf(o1[r]);
        }
    }
    const int q = w * 16 + l15;
    if (quad == 0 && q < 100)
        PL[((((size_t)s * 5 + e) * 16 + b) * 8 + h) * 128 + q] = lsum;
}

// ---------------- combine partials -> CTX bf16 -----------------------------
__launch_bounds__(256)
__global__ void combine(const us* __restrict__ PO, const float* __restrict__ PL,
                        us* __restrict__ CTX)
{
    const int blk = blockIdx.x;
    const int e   = blk / 1600;
    const int rem = blk - e * 1600;
    const int row = rem >> 4;
    const int b   = rem & 15;
    const int d   = threadIdx.x;
    const int h   = d >> 5;
    float O = 0.0f, L = 0.0f;
#pragma unroll
    for (int s = 0; s < 4; ++s) {
        O += bf2f(PO[(((size_t)((s * 5 + e) * 100 + row)) * 16 + b) * 256 + d]);
        L += PL[((((size_t)s * 5 + e) * 16 + b) * 8 + h) * 128 + row];
    }
    CTX[(((size_t)(e * 100 + row)) * 16 + b) * 256 + d] = f2bf(O / L);
}

// ---------------- gate + mix + residual + LayerNorm ------------------------
__launch_bounds__(256)
__global__ void finalize(const float* __restrict__ tgt, const float* __restrict__ w_gate,
                         const float* __restrict__ b_gate, const float* __restrict__ OUTf,
                         const float* __restrict__ gamma, const float* __restrict__ beta,
                         float* __restrict__ out)
{
    const int row = blockIdx.x;
    const int d = threadIdx.x;
    __shared__ float red[4];
    const float t = tgt[(size_t)row * 256 + d];

    float g[5];
#pragma unroll
    for (int e = 0; e < 5; ++e) {
        float part = t * w_gate[e * 256 + d];
#pragma unroll
        for (int off = 32; off >= 1; off >>= 1) part += __shfl_xor(part, off, 64);
        if ((d & 63) == 0) red[d >> 6] = part;
        __syncthreads();
        g[e] = red[0] + red[1] + red[2] + red[3] + b_gate[e];
        __syncthreads();
    }
    float mx = g[0];
#pragma unroll
    for (int e = 1; e < 5; ++e) mx = fmaxf(mx, g[e]);
    float sm = 0.0f;
#pragma unroll
    for (int e = 0; e < 5; ++e) { g[e] = __expf(g[e] - mx); sm += g[e]; }
    const float invs = 1.0f / sm;

    float mo = 0.0f;
#pragma unroll
    for (int e = 0; e < 5; ++e)
        mo += g[e] * invs * OUTf[((size_t)e * 1600 + row) * 256 + d];
    const float x = t + mo;

    float part = x;
#pragma unroll
    for (int off = 32; off >= 1; off >>= 1) part += __shfl_xor(part, off, 64);
    if ((d & 63) == 0) red[d >> 6] = part;
    __syncthreads();
    const float mean = (red[0] + red[1] + red[2] + red[3]) * (1.0f / 256.0f);
    __syncthreads();

    const float diff = x - mean;
    part = diff * diff;
#pragma unroll
    for (int off = 32; off >= 1; off >>= 1) part += __shfl_xor(part, off, 64);
    if ((d & 63) == 0) red[d >> 6] = part;
    __syncthreads();
    const float var = (red[0] + red[1] + red[2] + red[3]) * (1.0f / 256.0f);

    out[(size_t)row * 256 + d] = diff * rsqrtf(var + 1e-5f) * gamma[d] + beta[d];
}

// ---------------------------------------------------------------------------
extern "C" void kernel_launch(void* const* d_in, const int* in_sizes, int n_in,
                              void* d_out, int out_size, void* d_ws, size_t ws_size,
                              hipStream_t stream)
{
    const float* tgt    = (const float*)d_in[0];
    const float* mem    = (const float*)d_in[1];
    const float* qpos   = (const float*)d_in[2];
    const float* pos    = (const float*)d_in[3];
    const float* w_in   = (const float*)d_in[4];
    const float* b_in   = (const float*)d_in[5];
    const float* w_out  = (const float*)d_in[6];
    const float* b_out  = (const float*)d_in[7];
    const float* w_gate = (const float*)d_in[8];
    const float* b_gate = (const float*)d_in[9];
    const float* ln_g   = (const float*)d_in[10];
    const float* ln_b   = (const float*)d_in[11];
    float* out = (float*)d_out;

    char* p = (char*)d_ws;
    auto alloc = [&](size_t n) { char* r = p; p += (n + 255) & ~(size_t)255; return r; };

    us* Aq   = (us*)alloc(409600ull * 2);       // dead after gemm_qkv
    us* Ak   = (us*)alloc(4194304ull * 2);      // dead after gemm_qkv
    us* Av   = (us*)alloc(4194304ull * 2);      // dead after gemm_qkv
    us* Wb   = (us*)alloc(983040ull * 2);
    us* WOb  = (us*)alloc(327680ull * 2);
    us* Qb   = (us*)alloc(5ull * 409600 * 2);
    us* Kb   = (us*)alloc(5ull * 4194304 * 2);
    us* Vb   = (us*)alloc(5ull * 4194304 * 2);
    us* CTXb = (us*)alloc(5ull * 409600 * 2);
    float* OUTf = (float*)alloc(5ull * 409600 * 4);
    // Attention partials alias the dead cvt region (Aq..Av): 17.7 MB < 20.2 MB
    us*    PO = (us*)d_ws;                          // [4][5][100][16][256] bf16
    float* PL = (float*)((char*)d_ws + 16384000);   // [4*5*16*8][128] f32

    cvt_all<<<5776, 256, 0, stream>>>(tgt, qpos, mem, pos, w_in, w_out,
                                      Aq, Ak, Av, Wb, WOb);

    gemm_qkv<<<dim3(128, 2, 15), 256, 0, stream>>>(Aq, Ak, Av, Wb, b_in, Qb, Kb, Vb);

    attn<<<dim3(8, 80, 4), 512, 0, stream>>>(Qb, Kb, Vb, PO, PL);

    combine<<<8000, 256, 0, stream>>>(PO, PL, CTXb);

    gemm_o<<<dim3(13, 2, 5), 256, 0, stream>>>(CTXb, WOb, b_out, OUTf);

    finalize<<<1600, 256, 0, stream>>>(tgt, w_gate, b_gate, OUTf, ln_g, ln_b, out);
}

// Round 9
// 210.148 us; speedup vs baseline: 1.2542x; 1.0142x over previous
//
#include <hip/hip_runtime.h>

// ---------------------------------------------------------------------------
// MoE cross-attention decoder layer on MI355X (gfx950), bf16 MFMA pipeline.
// R9: fewer launches / smaller tail. cvt_all also computes the gate softmax
// (wave-per-row); combine is fused into gemm_og's A-staging (PO/PL ->
// normalize -> bf16 -> ds_write); finalize is gate-read + one fused
// sum/sumsq LN reduction. gemm_qkv and attn are unchanged from R8.
// ---------------------------------------------------------------------------

typedef __bf16 bf16x8 __attribute__((ext_vector_type(8)));
typedef float f32x4 __attribute__((ext_vector_type(4)));
typedef unsigned int u32x4 __attribute__((ext_vector_type(4)));
typedef unsigned int u32x2 __attribute__((ext_vector_type(2)));
typedef unsigned short u16x4 __attribute__((ext_vector_type(4)));
typedef unsigned short us;

__device__ __forceinline__ us f2bf(float f) {
    unsigned u = __builtin_bit_cast(unsigned, f);
    u += 0x7FFFu + ((u >> 16) & 1u);
    return (us)(u >> 16);
}

__device__ __forceinline__ unsigned pack2(float lo, float hi) {
    return (unsigned)f2bf(lo) | ((unsigned)f2bf(hi) << 16);
}

__device__ __forceinline__ float bf2f(us v) {
    unsigned u = ((unsigned)v) << 16;
    return __builtin_bit_cast(float, u);
}

__device__ __forceinline__ bf16x8 ld_bf8(const us* p) {
    return __builtin_bit_cast(bf16x8, *reinterpret_cast<const u32x4*>(p));
}

__device__ __forceinline__ void gld_lds16(const us* g, us* l) {
    __builtin_amdgcn_global_load_lds(
        (const __attribute__((address_space(1))) unsigned int*)g,
        (__attribute__((address_space(3))) unsigned int*)l, 16, 0, 0);
}

// ---------------- fused converts + gate softmax ----------------------------
// blocks [0,400): Aq rows (wave w = row 4*bid+w) + gate for that row.
__launch_bounds__(256)
__global__ void cvt_all(const float* __restrict__ tgt, const float* __restrict__ qpos,
                        const float* __restrict__ mem, const float* __restrict__ pos,
                        const float* __restrict__ w_in, const float* __restrict__ w_out,
                        const float* __restrict__ w_gate, const float* __restrict__ b_gate,
                        us* __restrict__ Aq, us* __restrict__ Ak, us* __restrict__ Av,
                        us* __restrict__ Wb, us* __restrict__ WOb,
                        float* __restrict__ Gate)
{
    const int bid = blockIdx.x;
    const int tid = threadIdx.x;
    if (bid < 400) {
        const int i = bid * 256 + tid;
        const int lane = tid & 63;
        const int row = i >> 6;                 // = 4*bid + wave
        f32x4 a = reinterpret_cast<const f32x4*>(tgt)[i];
        f32x4 b = reinterpret_cast<const f32x4*>(qpos)[i];
        u16x4 r;
#pragma unroll
        for (int j = 0; j < 4; ++j) r[j] = f2bf(a[j] + b[j]);
        reinterpret_cast<u16x4*>(Aq)[i] = r;
        // gate: dot(tgt_row, w_gate_e) across the wave
        float g[5];
#pragma unroll
        for (int e = 0; e < 5; ++e) {
            f32x4 wg = *reinterpret_cast<const f32x4*>(w_gate + e * 256 + 4 * lane);
            float p = a[0] * wg[0] + a[1] * wg[1] + a[2] * wg[2] + a[3] * wg[3];
#pragma unroll
            for (int off = 32; off >= 1; off >>= 1) p += __shfl_xor(p, off, 64);
            g[e] = p + b_gate[e];
        }
        float mx = g[0];
#pragma unroll
        for (int e = 1; e < 5; ++e) mx = fmaxf(mx, g[e]);
        float sm = 0.0f;
#pragma unroll
        for (int e = 0; e < 5; ++e) { g[e] = __expf(g[e] - mx); sm += g[e]; }
        const float invs = 1.0f / sm;
        if (lane == 0) {
#pragma unroll
            for (int e = 0; e < 5; ++e) Gate[row * 5 + e] = g[e] * invs;
        }
    } else if (bid < 4496) {
        int i = (bid - 400) * 256 + tid;
        f32x4 m = reinterpret_cast<const f32x4*>(mem)[i];
        f32x4 p = reinterpret_cast<const f32x4*>(pos)[i];
        u16x4 rk, rv;
#pragma unroll
        for (int j = 0; j < 4; ++j) { rk[j] = f2bf(m[j] + p[j]); rv[j] = f2bf(m[j]); }
        reinterpret_cast<u16x4*>(Ak)[i] = rk;
        reinterpret_cast<u16x4*>(Av)[i] = rv;
    } else if (bid < 5456) {
        int i = (bid - 4496) * 256 + tid;
        f32x4 a = reinterpret_cast<const f32x4*>(w_in)[i];
        u16x4 r;
#pragma unroll
        for (int j = 0; j < 4; ++j) r[j] = f2bf(a[j]);
        reinterpret_cast<u16x4*>(Wb)[i] = r;
    } else {
        int i = (bid - 5456) * 256 + tid;
        f32x4 a = reinterpret_cast<const f32x4*>(w_out)[i];
        u16x4 r;
#pragma unroll
        for (int j = 0; j < 4; ++j) r[j] = f2bf(a[j]);
        reinterpret_cast<u16x4*>(WOb)[i] = r;
    }
}

// ---------------- GEMM body (R8, unchanged): C = A * W^T -------------------
template <bool BF16OUT>
__device__ __forceinline__ void gemm_body(const us* __restrict__ A,
                                          const us* __restrict__ W,
                                          const float* __restrict__ bias,
                                          void* __restrict__ Cout,
                                          float scale, int M)
{
    const int row0 = blockIdx.x * 128;
    const int col0 = blockIdx.y * 128;
    __shared__ us As[2 * 8192];
    __shared__ us Bs[2 * 8192];
    const int tid  = threadIdx.x;
    const int lane = tid & 63;
    const int w    = tid >> 6;
    const int l15  = lane & 15;
    const int quad = lane >> 4;
    const int wm   = (w >> 1) * 64;
    const int wn   = (w & 1) * 64;
    const int srow = lane >> 3;
    const int gofs = ((lane & 7) ^ srow) * 8;

#pragma unroll
    for (int cc = 0; cc < 4; ++cc) {
        const int c = w * 4 + cc;
        const int row = c * 8 + srow;
        gld_lds16(A + (size_t)(row0 + row) * 256 + gofs, &As[c * 512]);
        gld_lds16(W + (size_t)(col0 + row) * 256 + gofs, &Bs[c * 512]);
    }
    __syncthreads();

    f32x4 acc[4][4] = {};

#pragma unroll
    for (int kt = 0; kt < 4; ++kt) {
        const int cur = (kt & 1) * 8192;
        if (kt < 3) {
            const int nxt = ((kt + 1) & 1) * 8192;
            const int k0 = (kt + 1) * 64;
#pragma unroll
            for (int cc = 0; cc < 4; ++cc) {
                const int c = w * 4 + cc;
                const int row = c * 8 + srow;
                gld_lds16(A + (size_t)(row0 + row) * 256 + k0 + gofs, &As[nxt + c * 512]);
                gld_lds16(W + (size_t)(col0 + row) * 256 + k0 + gofs, &Bs[nxt + c * 512]);
            }
        }
#pragma unroll
        for (int kh = 0; kh < 2; ++kh) {
            bf16x8 af[4], bf[4];
#pragma unroll
            for (int mi = 0; mi < 4; ++mi) {
                const int row = wm + mi * 16 + l15;
                const int seg = (kh * 4 + quad) ^ (row & 7);
                af[mi] = ld_bf8(&As[cur + row * 64 + seg * 8]);
            }
#pragma unroll
            for (int ni = 0; ni < 4; ++ni) {
                const int col = wn + ni * 16 + l15;
                const int seg = (kh * 4 + quad) ^ (col & 7);
                bf[ni] = ld_bf8(&Bs[cur + col * 64 + seg * 8]);
            }
#pragma unroll
            for (int mi = 0; mi < 4; ++mi)
#pragma unroll
                for (int ni = 0; ni < 4; ++ni)
                    acc[mi][ni] = __builtin_amdgcn_mfma_f32_16x16x32_bf16(bf[ni], af[mi], acc[mi][ni], 0, 0, 0);
        }
        if (kt < 3) __syncthreads();
    }

#pragma unroll
    for (int mi = 0; mi < 4; ++mi) {
        const int row = row0 + wm + mi * 16 + l15;
        if (row < M) {
#pragma unroll
            for (int ni = 0; ni < 4; ++ni) {
                const int colb = col0 + wn + ni * 16 + quad * 4;
                const f32x4 b4 = *reinterpret_cast<const f32x4*>(bias + colb);
                if constexpr (BF16OUT) {
                    u32x2 pk;
                    pk[0] = pack2((acc[mi][ni][0] + b4[0]) * scale,
                                  (acc[mi][ni][1] + b4[1]) * scale);
                    pk[1] = pack2((acc[mi][ni][2] + b4[2]) * scale,
                                  (acc[mi][ni][3] + b4[3]) * scale);
                    *reinterpret_cast<u32x2*>(reinterpret_cast<us*>(Cout) + (size_t)row * 256 + colb) = pk;
                } else {
                    f32x4 v;
#pragma unroll
                    for (int r = 0; r < 4; ++r) v[r] = (acc[mi][ni][r] + b4[r]) * scale;
                    *reinterpret_cast<f32x4*>(reinterpret_cast<float*>(Cout) + (size_t)row * 256 + colb) = v;
                }
            }
        }
    }
}

// merged Q/K/V projection: z 0..4 = Q (x<13), 5..9 = K, 10..14 = V
__launch_bounds__(256)
__global__ void gemm_qkv(const us* __restrict__ Aq, const us* __restrict__ Ak,
                         const us* __restrict__ Av, const us* __restrict__ Wb,
                         const float* __restrict__ b_in,
                         us* __restrict__ Qb, us* __restrict__ Kb, us* __restrict__ Vb)
{
    const int z = blockIdx.z;
    if (z < 5) {
        if (blockIdx.x >= 13) return;
        gemm_body<true>(Aq, Wb + (size_t)z * 196608, b_in + (size_t)z * 768,
                        Qb + (size_t)z * 409600, 0.17677669529663687f, 1600);
    } else if (z < 10) {
        const int e = z - 5;
        gemm_body<true>(Ak, Wb + 65536 + (size_t)e * 196608, b_in + (size_t)e * 768 + 256,
                        Kb + (size_t)e * 4194304, 1.0f, 16384);
    } else {
        const int e = z - 10;
        gemm_body<true>(Av, Wb + 131072 + (size_t)e * 196608, b_in + (size_t)e * 768 + 512,
                        Vb + (size_t)e * 4194304, 1.0f, 16384);
    }
}

// ---------------- out-proj GEMM with fused split-combine -------------------
// A-tile is built on the fly: CTX[row][d] = (sum_s PO_s[row][d]) / (sum_s PL_s)
// computed in registers, packed bf16, ds_write_b128 into the same swizzled
// LDS layout the fragment reads expect. W side unchanged (gld_lds, dbuf).
__launch_bounds__(256)
__global__ void gemm_og(const us* __restrict__ PO, const float* __restrict__ PL,
                        const us* __restrict__ WOb, const float* __restrict__ b_out,
                        float* __restrict__ OUTf)
{
    const int e = blockIdx.z;
    const us* W = WOb + (size_t)e * 65536;
    const float* bias = b_out + (size_t)e * 256;
    float* Cout = OUTf + (size_t)e * 409600;

    const int row0 = blockIdx.x * 128;
    const int col0 = blockIdx.y * 128;
    __shared__ us As[2 * 8192];
    __shared__ us Bs[2 * 8192];
    const int tid  = threadIdx.x;
    const int lane = tid & 63;
    const int w    = tid >> 6;
    const int l15  = lane & 15;
    const int quad = lane >> 4;
    const int wm   = (w >> 1) * 64;
    const int wn   = (w & 1) * 64;
    const int srow = lane >> 3;
    const int gofs = ((lane & 7) ^ srow) * 8;

    u32x4 POr[4][4];   // [chunk][split]
    float Lr[4];

    auto loadA = [&](int kt) {
#pragma unroll
        for (int cc = 0; cc < 4; ++cc) {
            const int c = w * 4 + cc;
            int grow = row0 + c * 8 + srow;
            if (grow > 1599) grow = 1599;
            const int d0 = kt * 64 + gofs;
            const size_t base = (size_t)e * 409600 + (size_t)grow * 256 + d0;
#pragma unroll
            for (int s = 0; s < 4; ++s)
                POr[cc][s] = *reinterpret_cast<const u32x4*>(PO + base + (size_t)s * 2048000);
            const int l = grow >> 4, bb = grow & 15, h = d0 >> 5;
            float L = 0.0f;
#pragma unroll
            for (int s = 0; s < 4; ++s)
                L += PL[((((size_t)s * 5 + e) * 16 + bb) * 8 + h) * 128 + l];
            Lr[cc] = L;
        }
    };
    auto writeA = [&](int buf) {
#pragma unroll
        for (int cc = 0; cc < 4; ++cc) {
            const float inv = 1.0f / Lr[cc];
            u32x4 pk;
#pragma unroll
            for (int j = 0; j < 4; ++j) {
                float v0 = 0.0f, v1 = 0.0f;
#pragma unroll
                for (int s = 0; s < 4; ++s) {
                    const unsigned u = POr[cc][s][j];
                    v0 += __builtin_bit_cast(float, u << 16);
                    v1 += __builtin_bit_cast(float, u & 0xffff0000u);
                }
                pk[j] = pack2(v0 * inv, v1 * inv);
            }
            *reinterpret_cast<u32x4*>(&As[buf * 8192 + (w * 4 + cc) * 512 + lane * 8]) = pk;
        }
    };
    auto loadW = [&](int buf, int kt) {
#pragma unroll
        for (int cc = 0; cc < 4; ++cc) {
            const int c = w * 4 + cc;
            const int row = c * 8 + srow;
            gld_lds16(W + (size_t)(col0 + row) * 256 + kt * 64 + gofs,
                      &Bs[buf * 8192 + c * 512]);
        }
    };

    loadA(0);
    loadW(0, 0);
    writeA(0);
    __syncthreads();

    f32x4 acc[4][4] = {};

#pragma unroll
    for (int kt = 0; kt < 4; ++kt) {
        const int cur = kt & 1;
        if (kt < 3) {
            loadA(kt + 1);
            loadW(cur ^ 1, kt + 1);
        }
#pragma unroll
        for (int kh = 0; kh < 2; ++kh) {
            bf16x8 af[4], bf[4];
#pragma unroll
            for (int mi = 0; mi < 4; ++mi) {
                const int row = wm + mi * 16 + l15;
                const int seg = (kh * 4 + quad) ^ (row & 7);
                af[mi] = ld_bf8(&As[cur * 8192 + row * 64 + seg * 8]);
            }
#pragma unroll
            for (int ni = 0; ni < 4; ++ni) {
                const int col = wn + ni * 16 + l15;
                const int seg = (kh * 4 + quad) ^ (col & 7);
                bf[ni] = ld_bf8(&Bs[cur * 8192 + col * 64 + seg * 8]);
            }
#pragma unroll
            for (int mi = 0; mi < 4; ++mi)
#pragma unroll
                for (int ni = 0; ni < 4; ++ni)
                    acc[mi][ni] = __builtin_amdgcn_mfma_f32_16x16x32_bf16(bf[ni], af[mi], acc[mi][ni], 0, 0, 0);
        }
        if (kt < 3) {
            writeA(cur ^ 1);
            __syncthreads();
        }
    }

#pragma unroll
    for (int mi = 0; mi < 4; ++mi) {
        const int row = row0 + wm + mi * 16 + l15;
        if (row < 1600) {
#pragma unroll
            for (int ni = 0; ni < 4; ++ni) {
                const int colb = col0 + wn + ni * 16 + quad * 4;
                const f32x4 b4 = *reinterpret_cast<const f32x4*>(bias + colb);
                f32x4 v;
#pragma unroll
                for (int r = 0; r < 4; ++r) v[r] = acc[mi][ni][r] + b4[r];
                *reinterpret_cast<f32x4*>(Cout + (size_t)row * 256 + colb) = v;
            }
        }
    }
}

// ---------------- split-K attention (unchanged from R4/R8) -----------------
__device__ __forceinline__ int vrow(int d) { return d * 264 + 8 * (d >> 3); }

__launch_bounds__(512)
__global__ void attn(const us* __restrict__ Qb, const us* __restrict__ Kb,
                     const us* __restrict__ Vb, us* __restrict__ PO,
                     float* __restrict__ PL)
{
    const int h = blockIdx.x;
    const int z = blockIdx.y;
    const int s = blockIdx.z;
    const int e = z >> 4, b = z & 15;
    const int tid  = threadIdx.x;
    const int w    = tid >> 6;
    const int lane = tid & 63;
    const int l15  = lane & 15, quad = lane >> 4;
    __shared__ us Ks[256 * 32];
    __shared__ us Vs[8464];
    __shared__ us Ps[7][16 * 40];

    const int key0 = s * 256;
    {
        const int kl  = lane >> 2;
        const int seg = lane & 3;
        const us* kg = Kb + ((size_t)((e * 1024 + key0 + w * 16 + kl) * 16 + b)) * 256
                          + h * 32 + seg * 8;
        gld_lds16(kg, &Ks[w * 512]);
        gld_lds16(kg + (size_t)128 * 16 * 256, &Ks[4096 + w * 512]);

        const int kv = tid >> 2;
        const int sg = tid & 3;
        const us* vg = Vb + ((size_t)((e * 1024 + key0 + kv) * 16 + b)) * 256
                          + h * 32 + sg * 8;
        u32x4 v0 = *reinterpret_cast<const u32x4*>(vg);
        u32x4 v1 = *reinterpret_cast<const u32x4*>(vg + (size_t)128 * 16 * 256);
#pragma unroll
        for (int j = 0; j < 4; ++j) {
            const int d0 = sg * 8 + 2 * j;
            const int e0 = vrow(d0);
            const int e1 = e0 + 264;
            Vs[e0 + kv]       = (us)(v0[j] & 0xffff);
            Vs[e1 + kv]       = (us)(v0[j] >> 16);
            Vs[e0 + 128 + kv] = (us)(v1[j] & 0xffff);
            Vs[e1 + 128 + kv] = (us)(v1[j] >> 16);
        }
    }
    u32x4 qraw = {0u, 0u, 0u, 0u};
    if (w < 7) {
        const int l = w * 16 + l15;
        if (l < 100)
            qraw = *reinterpret_cast<const u32x4*>(
                Qb + ((size_t)((e * 100 + l) * 16 + b)) * 256 + h * 32 + quad * 8);
    }
    const bf16x8 qf = __builtin_bit_cast(bf16x8, qraw);

    __syncthreads();

    if (w >= 7) return;

    const f32x4 zacc = {};
    f32x4 o0 = {}, o1 = {};
    float lsum = 0.0f;

    for (int c = 0; c < 8; ++c) {
        bf16x8 kf0 = ld_bf8(&Ks[(c * 32 + l15) * 32 + quad * 8]);
        bf16x8 kf1 = ld_bf8(&Ks[(c * 32 + 16 + l15) * 32 + quad * 8]);
        f32x4 s0 = __builtin_amdgcn_mfma_f32_16x16x32_bf16(kf0, qf, zacc, 0, 0, 0);
        f32x4 s1 = __builtin_amdgcn_mfma_f32_16x16x32_bf16(kf1, qf, zacc, 0, 0, 0);
        float p0[4], p1[4];
#pragma unroll
        for (int r = 0; r < 4; ++r) {
            p0[r] = __expf(s0[r]);
            p1[r] = __expf(s1[r]);
            lsum += p0[r] + p1[r];
        }
        u32x2 w0, w1;
        w0[0] = pack2(p0[0], p0[1]);
        w0[1] = pack2(p0[2], p0[3]);
        w1[0] = pack2(p1[0], p1[1]);
        w1[1] = pack2(p1[2], p1[3]);
        *reinterpret_cast<u32x2*>(&Ps[w][l15 * 40 + quad * 4])      = w0;
        *reinterpret_cast<u32x2*>(&Ps[w][l15 * 40 + 16 + quad * 4]) = w1;
        bf16x8 pf  = ld_bf8(&Ps[w][l15 * 40 + quad * 8]);
        bf16x8 vf0 = ld_bf8(&Vs[vrow(l15) + c * 32 + quad * 8]);
        bf16x8 vf1 = ld_bf8(&Vs[vrow(16 + l15) + c * 32 + quad * 8]);
        o0 = __builtin_amdgcn_mfma_f32_16x16x32_bf16(pf, vf0, o0, 0, 0, 0);
        o1 = __builtin_amdgcn_mfma_f32_16x16x32_bf16(pf, vf1, o1, 0, 0, 0);
    }

    lsum += __shfl_xor(lsum, 16, 64);
    lsum += __shfl_xor(lsum, 32, 64);

#pragma unroll
    for (int r = 0; r < 4; ++r) {
        const int row = w * 16 + quad * 4 + r;
        if (row < 100) {
            const size_t o = (((size_t)((s * 5 + e) * 100 + row)) * 16 + b) * 256 + h * 32;
            PO[o + l15]      = f2bf(o0[r]);
            PO[o + 16 + l15] = f2bf(o1[r]);
        }
    }
    const int q = w * 16 + l15;
    if (quad == 0 && q < 100)
        PL[((((size_t)s * 5 + e) * 16 + b) * 8 + h) * 128 + q] = lsum;
}

// ---------------- gate-weighted mix + residual + LayerNorm -----------------
__launch_bounds__(256)
__global__ void finalize(const float* __restrict__ tgt, const float* __restrict__ Gate,
                         const float* __restrict__ OUTf,
                         const float* __restrict__ gamma, const float* __restrict__ beta,
                         float* __restrict__ out)
{
    const int row = blockIdx.x;
    const int d = threadIdx.x;
    __shared__ float red[8];
    const float t = tgt[(size_t)row * 256 + d];

    float mo = 0.0f;
#pragma unroll
    for (int e = 0; e < 5; ++e)
        mo += Gate[row * 5 + e] * OUTf[((size_t)e * 1600 + row) * 256 + d];
    const float x = t + mo;

    float p1 = x, p2 = x * x;
#pragma unroll
    for (int off = 32; off >= 1; off >>= 1) {
        p1 += __shfl_xor(p1, off, 64);
        p2 += __shfl_xor(p2, off, 64);
    }
    if ((d & 63) == 0) { red[d >> 6] = p1; red[4 + (d >> 6)] = p2; }
    __syncthreads();
    const float mean = (red[0] + red[1] + red[2] + red[3]) * (1.0f / 256.0f);
    const float msq  = (red[4] + red[5] + red[6] + red[7]) * (1.0f / 256.0f);
    const float var  = msq - mean * mean;

    out[(size_t)row * 256 + d] = (x - mean) * rsqrtf(var + 1e-5f) * gamma[d] + beta[d];
}

// ---------------------------------------------------------------------------
extern "C" void kernel_launch(void* const* d_in, const int* in_sizes, int n_in,
                              void* d_out, int out_size, void* d_ws, size_t ws_size,
                              hipStream_t stream)
{
    const float* tgt    = (const float*)d_in[0];
    const float* mem    = (const float*)d_in[1];
    const float* qpos   = (const float*)d_in[2];
    const float* pos    = (const float*)d_in[3];
    const float* w_in   = (const float*)d_in[4];
    const float* b_in   = (const float*)d_in[5];
    const float* w_out  = (const float*)d_in[6];
    const float* b_out  = (const float*)d_in[7];
    const float* w_gate = (const float*)d_in[8];
    const float* b_gate = (const float*)d_in[9];
    const float* ln_g   = (const float*)d_in[10];
    const float* ln_b   = (const float*)d_in[11];
    float* out = (float*)d_out;

    char* p = (char*)d_ws;
    auto alloc = [&](size_t n) { char* r = p; p += (n + 255) & ~(size_t)255; return r; };

    us* Aq   = (us*)alloc(409600ull * 2);       // dead after gemm_qkv
    us* Ak   = (us*)alloc(4194304ull * 2);      // dead after gemm_qkv
    us* Av   = (us*)alloc(4194304ull * 2);      // dead after gemm_qkv
    us* Wb   = (us*)alloc(983040ull * 2);
    us* WOb  = (us*)alloc(327680ull * 2);
    us* Qb   = (us*)alloc(5ull * 409600 * 2);
    us* Kb   = (us*)alloc(5ull * 4194304 * 2);
    us* Vb   = (us*)alloc(5ull * 4194304 * 2);
    float* OUTf  = (float*)alloc(5ull * 409600 * 4);
    float* Gate  = (float*)alloc(1600ull * 5 * 4);
    // Attention partials alias the dead cvt region (Aq..Av): 16.4+0.33 < 17.7 MB
    us*    PO = (us*)d_ws;                          // [4][5][100][16][256] bf16
    float* PL = (float*)((char*)d_ws + 16384000);   // [4*5*16*8][128] f32

    cvt_all<<<5776, 256, 0, stream>>>(tgt, qpos, mem, pos, w_in, w_out,
                                      w_gate, b_gate, Aq, Ak, Av, Wb, WOb, Gate);

    gemm_qkv<<<dim3(128, 2, 15), 256, 0, stream>>>(Aq, Ak, Av, Wb, b_in, Qb, Kb, Vb);

    attn<<<dim3(8, 80, 4), 512, 0, stream>>>(Qb, Kb, Vb, PO, PL);

    gemm_og<<<dim3(13, 2, 5), 256, 0, stream>>>(PO, PL, WOb, b_out, OUTf);

    finalize<<<1600, 256, 0, stream>>>(tgt, Gate, OUTf, ln_g, ln_b, out);
}